// Round 5
// baseline (371.966 us; speedup 1.0000x reference)
//
#include <hip/hip_runtime.h>
#include <cstddef>
#include <cstdint>

// ---------------------------------------------------------------------------
// AttentionGoalState — round 5: conflict-free A-LDS layout in MFMA GEMM.
//
// Simplifications (exact up to fp rounding):
//   attn = softmax(KQ); Vn = V * attn.sum(axis=2) == V  (rowsums == 1)
//   -> K/Q GEMMs + S^2 softmax skipped entirely.
//
// GEMM: 128x128 tile, 4 waves, 4x4 frags of mfma_f32_16x16x32_bf16, BK=32,
// global_load_lds(16B).  BOTH A and B live in LDS as [kg][slot][8] so every
// fragment ds_read_b128 is 256B-contiguous across 16 lanes (2 lanes/bank =
// conflict-free, m136).  LDS dest stays linear (base + lane*16, required by
// global_load_lds); the k-chunk permutation is applied to the GLOBAL source
// address (wave w stages k-chunk w of rows l and l+64).
// ---------------------------------------------------------------------------

static constexpr int B_ = 8, TC = 6, TF = 4, DIN = 1024, DFF = 512, DOUT = 128;
static constexpr int HWP = 144;
static constexpr int P_CTX = B_ * TC * HWP;      // 6912
static constexpr int NF = B_ * TF;               // 32
static constexpr int P_FRM = NF * HWP;           // 4608
static constexpr int P_H1 = NF * 24 * 24;        // 18432
static constexpr int P_H2 = NF * 48 * 48;        // 73728
static constexpr int S2 = 48 * 48;               // 2304
static constexpr int NPOS = 3200;                // 8*4*10*10 conv3d outputs

// workspace offsets in float slots (phase-aliased; peak < 20.0M floats = 80MB)
static constexpr size_t OFF_X0   = 0;
static constexpr size_t OFF_X1   = 7077888;
static constexpr size_t OFF_XB   = 14155776;
static constexpr size_t OFF_VNB  = 17694720;
static constexpr size_t OFF_WB1  = 19464192;
static constexpr size_t OFF_WB2  = 19726336;
static constexpr size_t OFF_ST   = 19988480;
// conv3d phase (over X0/X1; XB still live):
static constexpr size_t OFF_GP   = 0;
static constexpr size_t OFF_TWB  = 11059200;
static constexpr size_t OFF_R    = 12828672;
// upsample/attn phase:
static constexpr size_t OFF_HP2  = 0;
static constexpr size_t OFF_HP1B = 9437184;
static constexpr size_t OFF_F0B  = 14155776;
static constexpr size_t OFF_W1B  = 16515072;
static constexpr size_t OFF_W2B  = 17563648;
static constexpr size_t OFF_SG   = 17694720;
static constexpr size_t OFF_PP   = 17768448;

typedef __attribute__((ext_vector_type(8))) short bf16x8;
typedef __attribute__((ext_vector_type(4))) float f32x4;
typedef __attribute__((ext_vector_type(4))) unsigned short us4;

__device__ __forceinline__ unsigned short f2b(float f) {
    union { float f; uint32_t u; } x{f};
    uint32_t r = x.u + 0x7FFFu + ((x.u >> 16) & 1u);  // RNE
    return (unsigned short)(r >> 16);
}

#define GL16(g, s)                                                        \
    __builtin_amdgcn_global_load_lds(                                     \
        (const __attribute__((address_space(1))) void*)(g),               \
        (__attribute__((address_space(3))) void*)(s), 16, 0, 0)

// --------------------------- helpers ---------------------------------------

__global__ __launch_bounds__(256) void zero_f32(float* p, int n) {
    int i = blockIdx.x * 256 + threadIdx.x;
    if (i < n) p[i] = 0.f;
}

// [F][C][HW] -> [F*HW][C], f32 and/or bf16 outputs
template <int WF32>
__global__ __launch_bounds__(256) void transpose_cm_pm(const float* __restrict__ in,
                                                       float* __restrict__ outF,
                                                       unsigned short* __restrict__ outB,
                                                       int C, int HW) {
    __shared__ float T[64][17];
    int tx = threadIdx.x, ty = threadIdx.y;
    int f = blockIdx.z, hw0 = blockIdx.x * 16, c0 = blockIdx.y * 64;
#pragma unroll
    for (int i = 0; i < 4; ++i)
        T[ty + 16 * i][tx] = in[((size_t)f * C + c0 + ty + 16 * i) * HW + hw0 + tx];
    __syncthreads();
#pragma unroll
    for (int i = 0; i < 4; ++i) {
        float v = T[tx + 16 * i][ty];
        size_t o = ((size_t)f * HW + hw0 + ty) * C + c0 + tx + 16 * i;
        if (WF32) outF[o] = v;
        outB[o] = f2b(v);
    }
}

// weight [O][C] -> Bp[((c>>3)*O + o)*8 + (c&7)]  (B[k=c][n=o])
__global__ __launch_bounds__(256) void wb_plain(const float* __restrict__ in,
                                                unsigned short* __restrict__ out,
                                                int O, int C) {
    int t = blockIdx.x * 256 + threadIdx.x;
    if (t >= O * C) return;
    int kr = t & 7, o = (t >> 3) % O, kg = (t >> 3) / O;
    out[t] = f2b(in[(size_t)o * C + kg * 8 + kr]);
}

// tp_w [128][1024][27] -> TWB[tap][((c>>3)*128 + o)*8 + (c&7)]
__global__ __launch_bounds__(256) void wb_conv(const float* __restrict__ tp,
                                               unsigned short* __restrict__ out) {
    int t = blockIdx.x * 256 + threadIdx.x;
    if (t >= 27 * 1024 * 128) return;
    int kr = t & 7, o = (t >> 3) & 127, kg = (t >> 10) & 127, tap = t >> 17;
    int c = kg * 8 + kr;
    out[t] = f2b(tp[((size_t)o * 1024 + c) * 27 + tap]);
}

// up_w [C][O][2][2] -> WB[d][((c>>3)*O + o)*8 + (c&7)]
__global__ __launch_bounds__(256) void wb_convT(const float* __restrict__ uw,
                                                unsigned short* __restrict__ out,
                                                int O, int C) {
    int t = blockIdx.x * 256 + threadIdx.x;
    if (t >= 4 * O * C) return;
    int kr = t & 7, o = (t >> 3) % O;
    int rest = (t >> 3) / O;
    int kg = rest % (C / 8), d = rest / (C / 8);
    int c = kg * 8 + kr;
    out[t] = f2b(uw[((size_t)c * O + o) * 4 + d]);
}

// --------------------------- MFMA GEMM --------------------------------------
// C[M,N] = epi(A[M,K] x B[K,N]).  A bf16 row-major (GATHER: im2col rows),
// B interleaved [K/8][N][8].  EPI bits: 1=bias 2=relu 4=resid(f32) 8=bf16 out.
// blockIdx.z: tap (conv3d) or quadrant d (convT REMAP).
template <int EPI, int REMAP, int GATHER>
__global__ __launch_bounds__(256) void gemm_mfma(
    const unsigned short* __restrict__ A, const unsigned short* __restrict__ Bp,
    const float* __restrict__ bias, const float* __restrict__ resid,
    void* __restrict__ Cv, int M, int N, int K,
    size_t bStrideZ, size_t cStrideZ,
    int inW, int inHW, int outW, int outSPP) {
    __shared__ unsigned short Al[128 * 32];  // [kg][row][8]: (kg*128+row)*8
    __shared__ unsigned short Bl[128 * 32];  // [kg][n][8]
    __shared__ int sPix[128];
    int tid = threadIdx.x;
    int w = tid >> 6, l = tid & 63;
    int m0 = blockIdx.y * 128, n0 = blockIdx.x * 128;
    int z = blockIdx.z;
    const unsigned short* Bpz = Bp + (size_t)z * bStrideZ;

    if (GATHER) {
        if (tid < 128) {
            int pos = m0 + tid;
            int ww = pos % 10;
            int r = pos / 10;
            int h = r % 10;
            r /= 10;
            int t = r & 3, b = r >> 2;
            int dt = z / 9, rr = z - dt * 9;
            int doff = dt * 144 + (rr / 3) * 12 + (rr % 3);
            sPix[tid] = ((b * 6 + t) * 12 + h) * 12 + ww + doff;
        }
        __syncthreads();
    }

    // A staging: wave w owns k-chunk w (8 elems) of this K-step; lane l
    // stages rows l and l+64.  LDS dest linear in lane (base + l*16).
    int grow0 = GATHER ? sPix[l] : (m0 + l);
    int grow1 = GATHER ? sPix[l + 64] : (m0 + l + 64);
    const unsigned short* ag0 = A + (size_t)grow0 * K + w * 8;
    const unsigned short* ag1 = A + (size_t)grow1 * K + w * 8;
    unsigned short* al0 = &Al[(w * 128 + l) * 8];
    unsigned short* al1 = &Al[(w * 128 + l + 64) * 8];
    // B: kg=w, n = c*64 + l
    const unsigned short* bg0 = Bpz + ((size_t)w * N + n0 + l) * 8;
    const unsigned short* bg1 = bg0 + (size_t)64 * 8;
    unsigned short* bl0 = &Bl[(w * 128 + l) * 8];
    unsigned short* bl1 = &Bl[(w * 128 + l + 64) * 8];
    size_t bstep = (size_t)32 * N;  // 4 k-groups * N * 8 elems

    int wr = w >> 1, wc = w & 1;
    int l15 = l & 15, lg = l >> 4;
    f32x4 acc[4][4];
#pragma unroll
    for (int mi = 0; mi < 4; ++mi)
#pragma unroll
        for (int ni = 0; ni < 4; ++ni) acc[mi][ni] = (f32x4){0.f, 0.f, 0.f, 0.f};

    for (int k0 = 0; k0 < K; k0 += 32) {
        GL16(ag0, al0);
        GL16(ag1, al1);
        GL16(bg0, bl0);
        GL16(bg1, bl1);
        ag0 += 32;
        ag1 += 32;
        bg0 += bstep;
        bg1 += bstep;
        __syncthreads();
        bf16x8 af[4], bf[4];
#pragma unroll
        for (int mi = 0; mi < 4; ++mi)
            af[mi] = *(const bf16x8*)&Al[(lg * 128 + wr * 64 + mi * 16 + l15) * 8];
#pragma unroll
        for (int ni = 0; ni < 4; ++ni)
            bf[ni] = *(const bf16x8*)&Bl[(lg * 128 + wc * 64 + ni * 16 + l15) * 8];
#pragma unroll
        for (int mi = 0; mi < 4; ++mi)
#pragma unroll
            for (int ni = 0; ni < 4; ++ni)
                acc[mi][ni] = __builtin_amdgcn_mfma_f32_16x16x32_bf16(
                    af[mi], bf[ni], acc[mi][ni], 0, 0, 0);
        __syncthreads();
    }

    // epilogue
    float bv[4];
#pragma unroll
    for (int ni = 0; ni < 4; ++ni)
        bv[ni] = (EPI & 1) ? bias[n0 + wc * 64 + ni * 16 + l15] : 0.f;
    float* Cf = (float*)Cv + (size_t)z * cStrideZ;
    unsigned short* Cb = (unsigned short*)Cv;
#pragma unroll
    for (int mi = 0; mi < 4; ++mi) {
#pragma unroll
        for (int r = 0; r < 4; ++r) {
            int m = m0 + wr * 64 + mi * 16 + lg * 4 + r;
            int orow = m;
            if (REMAP) {
                int ni_ = m / inHW;
                int rem = m - ni_ * inHW;
                int h = rem / inW, ww = rem - h * inW;
                orow = ni_ * outSPP + (2 * h + (z >> 1)) * outW + (2 * ww + (z & 1));
            }
#pragma unroll
            for (int ni = 0; ni < 4; ++ni) {
                int n = n0 + wc * 64 + ni * 16 + l15;
                float v = acc[mi][ni][r] + bv[ni];
                if (EPI & 2) v = fmaxf(v, 0.f);
                if (EPI & 4) v += resid[(size_t)m * N + n];
                if (EPI & 8)
                    Cb[(size_t)orow * N + n] = f2b(v);
                else
                    Cf[(size_t)orow * N + n] = v;
            }
        }
    }
}

// --------------------------- conv3d tail -------------------------------------

__global__ __launch_bounds__(256) void conv3_reduce(const float* __restrict__ Gp,
                                                    const float* __restrict__ bias,
                                                    float* __restrict__ R) {
    int idx = blockIdx.x * 256 + threadIdx.x;  // 3200*128
    float s = 0.f;
    for (int tap = 0; tap < 27; ++tap) s += Gp[(size_t)tap * (NPOS * 128) + idx];
    R[idx] = fmaxf(s + bias[idx & 127], 0.f);
}

__global__ __launch_bounds__(128) void goal_reduce(const float* __restrict__ R,
                                                   float* __restrict__ out) {
    int b = blockIdx.x, o = threadIdx.x;
    float s = 0.f;
    for (int i = 0; i < 400; ++i) s += R[(size_t)(b * 400 + i) * 128 + o];
    out[b * 128 + o] = s * (1.f / 400.f);
}

// --------------------------- BatchNorm --------------------------------------

__global__ __launch_bounds__(256) void bn_stats(const float* __restrict__ Y,
                                                float* __restrict__ st) {
    int tid = threadIdx.x;
    int p0 = blockIdx.x * 64;
    float s[4] = {0, 0, 0, 0}, q[4] = {0, 0, 0, 0};
    for (int pp = 0; pp < 64; ++pp) {
        const float* row = Y + (size_t)(p0 + pp) * 1024 + tid;
#pragma unroll
        for (int j = 0; j < 4; ++j) {
            float v = row[256 * j];
            s[j] += v;
            q[j] += v * v;
        }
    }
#pragma unroll
    for (int j = 0; j < 4; ++j) {
        atomicAdd(&st[tid + 256 * j], s[j]);
        atomicAdd(&st[1024 + tid + 256 * j], q[j]);
    }
}

__global__ __launch_bounds__(256) void bn_final(float* __restrict__ st,
                                                const float* __restrict__ gamma,
                                                const float* __restrict__ beta) {
    int c = blockIdx.x * 256 + threadIdx.x;
    if (c >= 1024) return;
    const float invn = 1.f / 6912.f;
    float mean = st[c] * invn;
    float var = st[1024 + c] * invn - mean * mean;
    float sc = gamma[c] * rsqrtf(var + 1e-5f);
    st[2048 + c] = sc;
    st[3072 + c] = beta[c] - mean * sc;
}

// BN apply in place on Y (f32) + bf16 copy to XB
__global__ __launch_bounds__(256) void bn_apply_b(float* __restrict__ Y,
                                                  unsigned short* __restrict__ XB,
                                                  const float* __restrict__ st) {
    const float* scale = st + 2048;
    const float* shift = st + 3072;
    int idx = blockIdx.x * 256 + threadIdx.x;
    float4* Y4 = (float4*)Y;
    int c0 = (idx & 255) << 2;
    float4 v = Y4[idx];
    v.x = v.x * scale[c0 + 0] + shift[c0 + 0];
    v.y = v.y * scale[c0 + 1] + shift[c0 + 1];
    v.z = v.z * scale[c0 + 2] + shift[c0 + 2];
    v.w = v.w * scale[c0 + 3] + shift[c0 + 3];
    Y4[idx] = v;
    us4 b;
    b.x = f2b(v.x);
    b.y = f2b(v.y);
    b.z = f2b(v.z);
    b.w = f2b(v.w);
    ((us4*)XB)[idx] = b;
}

// --------------------------- final goal/state attention ----------------------

__global__ __launch_bounds__(256) void attn_logits(const float* __restrict__ Hp2,
                                                   const float* __restrict__ out,
                                                   float* __restrict__ SG) {
    int n = blockIdx.y;
    int tid = threadIdx.x;
    int s = blockIdx.x * 16 + (tid >> 4);
    int l16 = tid & 15;
    const float4* row = (const float4*)(Hp2 + ((size_t)n * S2 + s) * 128 + l16 * 8);
    const float4* g = (const float4*)(out + (n & 7) * 128 + l16 * 8);
    float4 a0 = row[0], a1 = row[1], g0 = g[0], g1 = g[1];
    float dot = a0.x * g0.x + a0.y * g0.y + a0.z * g0.z + a0.w * g0.w +
                a1.x * g1.x + a1.y * g1.y + a1.z * g1.z + a1.w * g1.w;
    dot += __shfl_xor(dot, 1);
    dot += __shfl_xor(dot, 2);
    dot += __shfl_xor(dot, 4);
    dot += __shfl_xor(dot, 8);
    if (l16 == 0) SG[(size_t)n * S2 + s] = dot * 0.0883883476483184f;
}

__global__ __launch_bounds__(256) void attn_softmax(float* __restrict__ SG) {
    __shared__ float red[256];
    int n = blockIdx.x, tid = threadIdx.x;
    float* row = SG + (size_t)n * S2;
    float v[9];
    float lmax = -3.4e38f;
#pragma unroll
    for (int i = 0; i < 9; ++i) {
        v[i] = row[tid + 256 * i];
        lmax = fmaxf(lmax, v[i]);
    }
    red[tid] = lmax;
    __syncthreads();
    for (int off = 128; off > 0; off >>= 1) {
        if (tid < off) red[tid] = fmaxf(red[tid], red[tid + off]);
        __syncthreads();
    }
    float m = red[0];
    __syncthreads();
    float ls = 0.f;
#pragma unroll
    for (int i = 0; i < 9; ++i) {
        v[i] = expf(v[i] - m);
        ls += v[i];
    }
    red[tid] = ls;
    __syncthreads();
    for (int off = 128; off > 0; off >>= 1) {
        if (tid < off) red[tid] += red[tid + off];
        __syncthreads();
    }
    float inv = 1.f / red[0];
#pragma unroll
    for (int i = 0; i < 9; ++i) row[tid + 256 * i] = v[i] * inv;
}

__global__ __launch_bounds__(256) void attn_pv(const float* __restrict__ Hp2,
                                               const float* __restrict__ SG,
                                               float* __restrict__ PP) {
    int n = blockIdx.y;
    int sb = blockIdx.x;
    int tid = threadIdx.x;
    int d = tid & 127, half = tid >> 7;
    int s0 = sb * 128 + half * 64;
    float freq = expf(-(float)(d & ~1) * (9.210340371976184f / 128.f));
    bool odd = d & 1;
    const float* att = SG + (size_t)n * S2;
    float acc = 0.f;
    for (int i = 0; i < 64; ++i) {
        int s = s0 + i;
        float ang = (float)s * freq;
        float pe = odd ? cosf(ang) : sinf(ang);
        acc += att[s] * (Hp2[((size_t)n * S2 + s) * 128 + d] + pe);
    }
    PP[((size_t)n * 18 + sb) * 256 + tid] = acc;
}

__global__ __launch_bounds__(128) void attn_pv_reduce(const float* __restrict__ PP,
                                                      float* __restrict__ out) {
    int n = blockIdx.x, d = threadIdx.x;
    float s = 0.f;
    for (int i = 0; i < 18; ++i) {
        const float* p = PP + ((size_t)n * 18 + i) * 256;
        s += p[d] + p[128 + d];
    }
    out[1024 + n * 128 + d] = s;
}

// --------------------------- launch ------------------------------------------

extern "C" void kernel_launch(void* const* d_in, const int* in_sizes, int n_in,
                              void* d_out, int out_size, void* d_ws, size_t ws_size,
                              hipStream_t stream) {
    const float* context = (const float*)d_in[0];
    const float* frame = (const float*)d_in[1];
    const float* Vw = (const float*)d_in[6];
    const float* Vb = (const float*)d_in[7];
    const float* Ow = (const float*)d_in[8];
    const float* Ob = (const float*)d_in[9];
    const float* gamma = (const float*)d_in[10];
    const float* beta = (const float*)d_in[11];
    const float* tpw = (const float*)d_in[12];
    const float* tpb = (const float*)d_in[13];
    const float* u1w = (const float*)d_in[14];
    const float* u1b = (const float*)d_in[15];
    const float* u2w = (const float*)d_in[16];
    const float* u2b = (const float*)d_in[17];
    float* ws = (float*)d_ws;
    float* out = (float*)d_out;

    float* X0 = ws + OFF_X0;
    float* X1 = ws + OFF_X1;
    unsigned short* XB = (unsigned short*)(ws + OFF_XB);
    unsigned short* VNB = (unsigned short*)(ws + OFF_VNB);
    unsigned short* WB1 = (unsigned short*)(ws + OFF_WB1);
    unsigned short* WB2 = (unsigned short*)(ws + OFF_WB2);
    float* ST = ws + OFF_ST;
    float* GP = ws + OFF_GP;
    unsigned short* TWB = (unsigned short*)(ws + OFF_TWB);
    float* R = ws + OFF_R;
    float* HP2 = ws + OFF_HP2;
    unsigned short* HP1B = (unsigned short*)(ws + OFF_HP1B);
    unsigned short* F0B = (unsigned short*)(ws + OFF_F0B);
    unsigned short* W1B = (unsigned short*)(ws + OFF_W1B);
    unsigned short* W2B = (unsigned short*)(ws + OFF_W2B);
    float* SG = ws + OFF_SG;
    float* PP = ws + OFF_PP;

    // context [8][6][1024][144] -> X0 f32 + XB bf16 (pixel-major)
    transpose_cm_pm<1><<<dim3(HWP / 16, DIN / 64, B_ * TC), dim3(16, 16), 0, stream>>>(
        context, X0, XB, DIN, HWP);

    float* Xin = X0;
    float* Y = X1;
    for (int l = 0; l < 2; ++l) {
        wb_plain<<<(DFF * DIN) / 256, 256, 0, stream>>>(Vw + (size_t)l * DFF * DIN, WB1, DFF, DIN);
        wb_plain<<<(DIN * DFF) / 256, 256, 0, stream>>>(Ow + (size_t)l * DIN * DFF, WB2, DIN, DFF);
        // VN = relu(X*Vw^T + Vb)  [bf16 out]
        gemm_mfma<11, 0, 0><<<dim3(DFF / 128, P_CTX / 128, 1), 256, 0, stream>>>(
            XB, WB1, Vb + l * DFF, nullptr, VNB, P_CTX, DFF, DIN, 0, 0, 0, 0, 0, 0);
        // Y = X + relu(VN*Ow^T + Ob)  [f32 out]
        gemm_mfma<7, 0, 0><<<dim3(DIN / 128, P_CTX / 128, 1), 256, 0, stream>>>(
            VNB, WB2, Ob + l * DIN, Xin, Y, P_CTX, DIN, DFF, 0, 0, 0, 0, 0, 0);
        // BatchNorm (training-mode stats) in place on Y; bf16 copy -> XB
        zero_f32<<<8, 256, 0, stream>>>(ST, 2048);
        bn_stats<<<P_CTX / 64, 256, 0, stream>>>(Y, ST);
        bn_final<<<4, 256, 0, stream>>>(ST, gamma + l * DIN, beta + l * DIN);
        bn_apply_b<<<(P_CTX * DIN / 4) / 256, 256, 0, stream>>>(Y, XB, ST);
        float* t = Xin;
        Xin = Y;
        Y = t;
    }

    // temporal pool: split-K GEMM over 27 taps (A rows gathered from XB)
    wb_conv<<<(27 * DIN * DOUT) / 256, 256, 0, stream>>>(tpw, TWB);
    gemm_mfma<0, 0, 1><<<dim3(1, NPOS / 128, 27), 256, 0, stream>>>(
        XB, TWB, nullptr, nullptr, GP, NPOS, DOUT, DIN,
        (size_t)DIN / 8 * DOUT * 8, (size_t)NPOS * DOUT, 0, 0, 0, 0);
    conv3_reduce<<<(NPOS * DOUT) / 256, 256, 0, stream>>>(GP, tpb, R);
    goal_reduce<<<8, 128, 0, stream>>>(R, out);

    // frame upsample path (bf16 activations throughout)
    transpose_cm_pm<0><<<dim3(HWP / 16, DIN / 64, NF), dim3(16, 16), 0, stream>>>(
        frame, nullptr, F0B, DIN, HWP);
    wb_convT<<<(4 * DIN * DFF) / 256, 256, 0, stream>>>(u1w, W1B, DFF, DIN);
    wb_convT<<<(4 * DFF * DOUT) / 256, 256, 0, stream>>>(u2w, W2B, DOUT, DFF);
    // up1: relu(convT1), 4 quadrants via blockIdx.z, bf16 out with row remap
    gemm_mfma<11, 1, 0><<<dim3(DFF / 128, P_FRM / 128, 4), 256, 0, stream>>>(
        F0B, W1B, u1b, nullptr, HP1B, P_FRM, DFF, DIN,
        (size_t)DIN / 8 * DFF * 8, 0, 12, 144, 24, 576);
    // up2: convT2 (no relu), f32 out with row remap -> HP2
    gemm_mfma<1, 1, 0><<<dim3(DOUT / 128, P_H1 / 128, 4), 256, 0, stream>>>(
        HP1B, W2B, u2b, nullptr, HP2, P_H1, DOUT, DFF,
        (size_t)DFF / 8 * DOUT * 8, 0, 24, 576, 48, 2304);

    // final goal/state attention
    attn_logits<<<dim3(S2 / 16, NF), 256, 0, stream>>>(HP2, out, SG);
    attn_softmax<<<NF, 256, 0, stream>>>(SG);
    attn_pv<<<dim3(18, NF), 256, 0, stream>>>(HP2, SG, PP);
    attn_pv_reduce<<<NF, 128, 0, stream>>>(PP, out);
}

// Round 6
// 363.314 us; speedup vs baseline: 1.0238x; 1.0238x over previous
//
#include <hip/hip_runtime.h>
#include <cstddef>
#include <cstdint>

// ---------------------------------------------------------------------------
// AttentionGoalState — round 6: 2-phase pipelined MFMA GEMM (counted vmcnt).
//
// Simplifications (exact up to fp rounding):
//   attn = softmax(KQ); Vn = V * attn.sum(axis=2) == V  (rowsums == 1)
//   -> K/Q GEMMs + S^2 softmax skipped entirely.
//
// GEMM: 128x128 tile, 4 waves, 4x4 frags of mfma_f32_16x16x32_bf16, BK=32,
// global_load_lds(16B), DOUBLE-buffered LDS.  K-loop per iter:
//   STAGE(next buf)  -> s_waitcnt vmcnt(4)  (cur's 4 loads done, next's 4
//   stay in flight)  -> raw s_barrier -> ds_read+MFMA(cur) -> s_barrier.
// Raw s_barrier (not __syncthreads) avoids the compiler's vmcnt(0) drain.
// Both A and B in LDS as [kg][slot][8]: fragment ds_read_b128 is 256B-
// contiguous across 16 lanes = conflict-free (verified R5: conflicts == 0).
// ---------------------------------------------------------------------------

static constexpr int B_ = 8, TC = 6, TF = 4, DIN = 1024, DFF = 512, DOUT = 128;
static constexpr int HWP = 144;
static constexpr int P_CTX = B_ * TC * HWP;      // 6912
static constexpr int NF = B_ * TF;               // 32
static constexpr int P_FRM = NF * HWP;           // 4608
static constexpr int P_H1 = NF * 24 * 24;        // 18432
static constexpr int P_H2 = NF * 48 * 48;        // 73728
static constexpr int S2 = 48 * 48;               // 2304
static constexpr int NPOS = 3200;                // 8*4*10*10 conv3d outputs

// workspace offsets in float slots (phase-aliased; peak < 20.0M floats = 80MB)
static constexpr size_t OFF_X0   = 0;
static constexpr size_t OFF_X1   = 7077888;
static constexpr size_t OFF_XB   = 14155776;
static constexpr size_t OFF_VNB  = 17694720;
static constexpr size_t OFF_WB1  = 19464192;
static constexpr size_t OFF_WB2  = 19726336;
static constexpr size_t OFF_ST   = 19988480;
// conv3d phase (over X0/X1; XB still live):
static constexpr size_t OFF_GP   = 0;
static constexpr size_t OFF_TWB  = 11059200;
static constexpr size_t OFF_R    = 12828672;
// upsample/attn phase:
static constexpr size_t OFF_HP2  = 0;
static constexpr size_t OFF_HP1B = 9437184;
static constexpr size_t OFF_F0B  = 14155776;
static constexpr size_t OFF_W1B  = 16515072;
static constexpr size_t OFF_W2B  = 17563648;
static constexpr size_t OFF_SG   = 17694720;
static constexpr size_t OFF_PP   = 17768448;

typedef __attribute__((ext_vector_type(8))) short bf16x8;
typedef __attribute__((ext_vector_type(4))) float f32x4;
typedef __attribute__((ext_vector_type(4))) unsigned short us4;

__device__ __forceinline__ unsigned short f2b(float f) {
    union { float f; uint32_t u; } x{f};
    uint32_t r = x.u + 0x7FFFu + ((x.u >> 16) & 1u);  // RNE
    return (unsigned short)(r >> 16);
}

#define GL16(g, s)                                                        \
    __builtin_amdgcn_global_load_lds(                                     \
        (const __attribute__((address_space(1))) void*)(g),               \
        (__attribute__((address_space(3))) void*)(s), 16, 0, 0)

// --------------------------- helpers ---------------------------------------

__global__ __launch_bounds__(256) void zero_f32(float* p, int n) {
    int i = blockIdx.x * 256 + threadIdx.x;
    if (i < n) p[i] = 0.f;
}

// [F][C][HW] -> [F*HW][C], f32 and/or bf16 outputs
template <int WF32>
__global__ __launch_bounds__(256) void transpose_cm_pm(const float* __restrict__ in,
                                                       float* __restrict__ outF,
                                                       unsigned short* __restrict__ outB,
                                                       int C, int HW) {
    __shared__ float T[64][17];
    int tx = threadIdx.x, ty = threadIdx.y;
    int f = blockIdx.z, hw0 = blockIdx.x * 16, c0 = blockIdx.y * 64;
#pragma unroll
    for (int i = 0; i < 4; ++i)
        T[ty + 16 * i][tx] = in[((size_t)f * C + c0 + ty + 16 * i) * HW + hw0 + tx];
    __syncthreads();
#pragma unroll
    for (int i = 0; i < 4; ++i) {
        float v = T[tx + 16 * i][ty];
        size_t o = ((size_t)f * HW + hw0 + ty) * C + c0 + tx + 16 * i;
        if (WF32) outF[o] = v;
        outB[o] = f2b(v);
    }
}

// weight [O][C] -> Bp[((c>>3)*O + o)*8 + (c&7)]  (B[k=c][n=o])
__global__ __launch_bounds__(256) void wb_plain(const float* __restrict__ in,
                                                unsigned short* __restrict__ out,
                                                int O, int C) {
    int t = blockIdx.x * 256 + threadIdx.x;
    if (t >= O * C) return;
    int kr = t & 7, o = (t >> 3) % O, kg = (t >> 3) / O;
    out[t] = f2b(in[(size_t)o * C + kg * 8 + kr]);
}

// tp_w [128][1024][27] -> TWB[tap][((c>>3)*128 + o)*8 + (c&7)]
__global__ __launch_bounds__(256) void wb_conv(const float* __restrict__ tp,
                                               unsigned short* __restrict__ out) {
    int t = blockIdx.x * 256 + threadIdx.x;
    if (t >= 27 * 1024 * 128) return;
    int kr = t & 7, o = (t >> 3) & 127, kg = (t >> 10) & 127, tap = t >> 17;
    int c = kg * 8 + kr;
    out[t] = f2b(tp[((size_t)o * 1024 + c) * 27 + tap]);
}

// up_w [C][O][2][2] -> WB[d][((c>>3)*O + o)*8 + (c&7)]
__global__ __launch_bounds__(256) void wb_convT(const float* __restrict__ uw,
                                                unsigned short* __restrict__ out,
                                                int O, int C) {
    int t = blockIdx.x * 256 + threadIdx.x;
    if (t >= 4 * O * C) return;
    int kr = t & 7, o = (t >> 3) % O;
    int rest = (t >> 3) / O;
    int kg = rest % (C / 8), d = rest / (C / 8);
    int c = kg * 8 + kr;
    out[t] = f2b(uw[((size_t)c * O + o) * 4 + d]);
}

// --------------------------- MFMA GEMM --------------------------------------
// C[M,N] = epi(A[M,K] x B[K,N]).  A bf16 row-major (GATHER: im2col rows),
// B interleaved [K/8][N][8].  EPI bits: 1=bias 2=relu 4=resid(f32) 8=bf16 out.
// blockIdx.z: tap (conv3d) or quadrant d (convT REMAP).
template <int EPI, int REMAP, int GATHER>
__global__ __launch_bounds__(256) void gemm_mfma(
    const unsigned short* __restrict__ A, const unsigned short* __restrict__ Bp,
    const float* __restrict__ bias, const float* __restrict__ resid,
    void* __restrict__ Cv, int M, int N, int K,
    size_t bStrideZ, size_t cStrideZ,
    int inW, int inHW, int outW, int outSPP) {
    __shared__ unsigned short Al[2][128 * 32];  // [kg][row][8]: (kg*128+row)*8
    __shared__ unsigned short Bl[2][128 * 32];  // [kg][n][8]
    __shared__ int sPix[128];
    int tid = threadIdx.x;
    int w = tid >> 6, l = tid & 63;
    int m0 = blockIdx.y * 128, n0 = blockIdx.x * 128;
    int z = blockIdx.z;
    const unsigned short* Bpz = Bp + (size_t)z * bStrideZ;

    if (GATHER) {
        if (tid < 128) {
            int pos = m0 + tid;
            int ww = pos % 10;
            int r = pos / 10;
            int h = r % 10;
            r /= 10;
            int t = r & 3, b = r >> 2;
            int dt = z / 9, rr = z - dt * 9;
            int doff = dt * 144 + (rr / 3) * 12 + (rr % 3);
            sPix[tid] = ((b * 6 + t) * 12 + h) * 12 + ww + doff;
        }
        __syncthreads();
    }

    int wr = w >> 1, wc = w & 1;
    int l15 = l & 15, lg = l >> 4;

    // bias preload BEFORE staging so vmcnt FIFO analysis in the loop holds.
    float bv[4];
#pragma unroll
    for (int ni = 0; ni < 4; ++ni)
        bv[ni] = (EPI & 1) ? bias[n0 + wc * 64 + ni * 16 + l15] : 0.f;
    asm volatile("s_waitcnt vmcnt(0)" ::: "memory");

    // A staging: wave w owns k-chunk w (8 elems) of this K-step; lane l
    // stages rows l and l+64.  LDS dest linear in lane (required by GL16).
    int grow0 = GATHER ? sPix[l] : (m0 + l);
    int grow1 = GATHER ? sPix[l + 64] : (m0 + l + 64);
    const unsigned short* ag0 = A + (size_t)grow0 * K + w * 8;
    const unsigned short* ag1 = A + (size_t)grow1 * K + w * 8;
    const unsigned short* bg0 = Bpz + ((size_t)w * N + n0 + l) * 8;
    const unsigned short* bg1 = bg0 + (size_t)64 * 8;
    size_t bstep = (size_t)32 * N;  // 4 k-groups * N * 8 elems
    const int aoff = (w * 128 + l) * 8;

    f32x4 acc[4][4];
#pragma unroll
    for (int mi = 0; mi < 4; ++mi)
#pragma unroll
        for (int ni = 0; ni < 4; ++ni) acc[mi][ni] = (f32x4){0.f, 0.f, 0.f, 0.f};

    int nt = K >> 5;
    // prologue: stage buffer 0
    GL16(ag0, &Al[0][aoff]);
    GL16(ag1, &Al[0][aoff + 512]);
    GL16(bg0, &Bl[0][aoff]);
    GL16(bg1, &Bl[0][aoff + 512]);
    ag0 += 32;
    ag1 += 32;
    bg0 += bstep;
    bg1 += bstep;

    for (int t = 0; t < nt; ++t) {
        int cur = t & 1;
        if (t + 1 < nt) {
            int nx = cur ^ 1;
            GL16(ag0, &Al[nx][aoff]);
            GL16(ag1, &Al[nx][aoff + 512]);
            GL16(bg0, &Bl[nx][aoff]);
            GL16(bg1, &Bl[nx][aoff + 512]);
            ag0 += 32;
            ag1 += 32;
            bg0 += bstep;
            bg1 += bstep;
            // cur's 4 loads done; next's 4 stay in flight across the barrier
            asm volatile("s_waitcnt vmcnt(4)" ::: "memory");
        } else {
            asm volatile("s_waitcnt vmcnt(0)" ::: "memory");
        }
        __builtin_amdgcn_s_barrier();
        __builtin_amdgcn_sched_barrier(0);
        bf16x8 af[4], bf[4];
#pragma unroll
        for (int mi = 0; mi < 4; ++mi)
            af[mi] = *(const bf16x8*)&Al[cur][(lg * 128 + wr * 64 + mi * 16 + l15) * 8];
#pragma unroll
        for (int ni = 0; ni < 4; ++ni)
            bf[ni] = *(const bf16x8*)&Bl[cur][(lg * 128 + wc * 64 + ni * 16 + l15) * 8];
#pragma unroll
        for (int mi = 0; mi < 4; ++mi)
#pragma unroll
            for (int ni = 0; ni < 4; ++ni)
                acc[mi][ni] = __builtin_amdgcn_mfma_f32_16x16x32_bf16(
                    af[mi], bf[ni], acc[mi][ni], 0, 0, 0);
        __builtin_amdgcn_sched_barrier(0);
        __builtin_amdgcn_s_barrier();
    }

    // epilogue
    float* Cf = (float*)Cv + (size_t)z * cStrideZ;
    unsigned short* Cb = (unsigned short*)Cv;
#pragma unroll
    for (int mi = 0; mi < 4; ++mi) {
#pragma unroll
        for (int r = 0; r < 4; ++r) {
            int m = m0 + wr * 64 + mi * 16 + lg * 4 + r;
            int orow = m;
            if (REMAP) {
                int ni_ = m / inHW;
                int rem = m - ni_ * inHW;
                int h = rem / inW, ww = rem - h * inW;
                orow = ni_ * outSPP + (2 * h + (z >> 1)) * outW + (2 * ww + (z & 1));
            }
#pragma unroll
            for (int ni = 0; ni < 4; ++ni) {
                int n = n0 + wc * 64 + ni * 16 + l15;
                float v = acc[mi][ni][r] + bv[ni];
                if (EPI & 2) v = fmaxf(v, 0.f);
                if (EPI & 4) v += resid[(size_t)m * N + n];
                if (EPI & 8)
                    Cb[(size_t)orow * N + n] = f2b(v);
                else
                    Cf[(size_t)orow * N + n] = v;
            }
        }
    }
}

// --------------------------- conv3d tail -------------------------------------

__global__ __launch_bounds__(256) void conv3_reduce(const float* __restrict__ Gp,
                                                    const float* __restrict__ bias,
                                                    float* __restrict__ R) {
    int idx = blockIdx.x * 256 + threadIdx.x;  // 3200*128
    float s = 0.f;
    for (int tap = 0; tap < 27; ++tap) s += Gp[(size_t)tap * (NPOS * 128) + idx];
    R[idx] = fmaxf(s + bias[idx & 127], 0.f);
}

__global__ __launch_bounds__(128) void goal_reduce(const float* __restrict__ R,
                                                   float* __restrict__ out) {
    int b = blockIdx.x, o = threadIdx.x;
    float s = 0.f;
    for (int i = 0; i < 400; ++i) s += R[(size_t)(b * 400 + i) * 128 + o];
    out[b * 128 + o] = s * (1.f / 400.f);
}

// --------------------------- BatchNorm --------------------------------------

__global__ __launch_bounds__(256) void bn_stats(const float* __restrict__ Y,
                                                float* __restrict__ st) {
    int tid = threadIdx.x;
    int p0 = blockIdx.x * 64;
    float s[4] = {0, 0, 0, 0}, q[4] = {0, 0, 0, 0};
    for (int pp = 0; pp < 64; ++pp) {
        const float* row = Y + (size_t)(p0 + pp) * 1024 + tid;
#pragma unroll
        for (int j = 0; j < 4; ++j) {
            float v = row[256 * j];
            s[j] += v;
            q[j] += v * v;
        }
    }
#pragma unroll
    for (int j = 0; j < 4; ++j) {
        atomicAdd(&st[tid + 256 * j], s[j]);
        atomicAdd(&st[1024 + tid + 256 * j], q[j]);
    }
}

__global__ __launch_bounds__(256) void bn_final(float* __restrict__ st,
                                                const float* __restrict__ gamma,
                                                const float* __restrict__ beta) {
    int c = blockIdx.x * 256 + threadIdx.x;
    if (c >= 1024) return;
    const float invn = 1.f / 6912.f;
    float mean = st[c] * invn;
    float var = st[1024 + c] * invn - mean * mean;
    float sc = gamma[c] * rsqrtf(var + 1e-5f);
    st[2048 + c] = sc;
    st[3072 + c] = beta[c] - mean * sc;
}

// BN apply in place on Y (f32) + bf16 copy to XB
__global__ __launch_bounds__(256) void bn_apply_b(float* __restrict__ Y,
                                                  unsigned short* __restrict__ XB,
                                                  const float* __restrict__ st) {
    const float* scale = st + 2048;
    const float* shift = st + 3072;
    int idx = blockIdx.x * 256 + threadIdx.x;
    float4* Y4 = (float4*)Y;
    int c0 = (idx & 255) << 2;
    float4 v = Y4[idx];
    v.x = v.x * scale[c0 + 0] + shift[c0 + 0];
    v.y = v.y * scale[c0 + 1] + shift[c0 + 1];
    v.z = v.z * scale[c0 + 2] + shift[c0 + 2];
    v.w = v.w * scale[c0 + 3] + shift[c0 + 3];
    Y4[idx] = v;
    us4 b;
    b.x = f2b(v.x);
    b.y = f2b(v.y);
    b.z = f2b(v.z);
    b.w = f2b(v.w);
    ((us4*)XB)[idx] = b;
}

// --------------------------- final goal/state attention ----------------------

__global__ __launch_bounds__(256) void attn_logits(const float* __restrict__ Hp2,
                                                   const float* __restrict__ out,
                                                   float* __restrict__ SG) {
    int n = blockIdx.y;
    int tid = threadIdx.x;
    int s = blockIdx.x * 16 + (tid >> 4);
    int l16 = tid & 15;
    const float4* row = (const float4*)(Hp2 + ((size_t)n * S2 + s) * 128 + l16 * 8);
    const float4* g = (const float4*)(out + (n & 7) * 128 + l16 * 8);
    float4 a0 = row[0], a1 = row[1], g0 = g[0], g1 = g[1];
    float dot = a0.x * g0.x + a0.y * g0.y + a0.z * g0.z + a0.w * g0.w +
                a1.x * g1.x + a1.y * g1.y + a1.z * g1.z + a1.w * g1.w;
    dot += __shfl_xor(dot, 1);
    dot += __shfl_xor(dot, 2);
    dot += __shfl_xor(dot, 4);
    dot += __shfl_xor(dot, 8);
    if (l16 == 0) SG[(size_t)n * S2 + s] = dot * 0.0883883476483184f;
}

__global__ __launch_bounds__(256) void attn_softmax(float* __restrict__ SG) {
    __shared__ float red[256];
    int n = blockIdx.x, tid = threadIdx.x;
    float* row = SG + (size_t)n * S2;
    float v[9];
    float lmax = -3.4e38f;
#pragma unroll
    for (int i = 0; i < 9; ++i) {
        v[i] = row[tid + 256 * i];
        lmax = fmaxf(lmax, v[i]);
    }
    red[tid] = lmax;
    __syncthreads();
    for (int off = 128; off > 0; off >>= 1) {
        if (tid < off) red[tid] = fmaxf(red[tid], red[tid + off]);
        __syncthreads();
    }
    float m = red[0];
    __syncthreads();
    float ls = 0.f;
#pragma unroll
    for (int i = 0; i < 9; ++i) {
        v[i] = expf(v[i] - m);
        ls += v[i];
    }
    red[tid] = ls;
    __syncthreads();
    for (int off = 128; off > 0; off >>= 1) {
        if (tid < off) red[tid] += red[tid + off];
        __syncthreads();
    }
    float inv = 1.f / red[0];
#pragma unroll
    for (int i = 0; i < 9; ++i) row[tid + 256 * i] = v[i] * inv;
}

__global__ __launch_bounds__(256) void attn_pv(const float* __restrict__ Hp2,
                                               const float* __restrict__ SG,
                                               float* __restrict__ PP) {
    int n = blockIdx.y;
    int sb = blockIdx.x;
    int tid = threadIdx.x;
    int d = tid & 127, half = tid >> 7;
    int s0 = sb * 128 + half * 64;
    float freq = expf(-(float)(d & ~1) * (9.210340371976184f / 128.f));
    bool odd = d & 1;
    const float* att = SG + (size_t)n * S2;
    float acc = 0.f;
    for (int i = 0; i < 64; ++i) {
        int s = s0 + i;
        float ang = (float)s * freq;
        float pe = odd ? cosf(ang) : sinf(ang);
        acc += att[s] * (Hp2[((size_t)n * S2 + s) * 128 + d] + pe);
    }
    PP[((size_t)n * 18 + sb) * 256 + tid] = acc;
}

__global__ __launch_bounds__(128) void attn_pv_reduce(const float* __restrict__ PP,
                                                      float* __restrict__ out) {
    int n = blockIdx.x, d = threadIdx.x;
    float s = 0.f;
    for (int i = 0; i < 18; ++i) {
        const float* p = PP + ((size_t)n * 18 + i) * 256;
        s += p[d] + p[128 + d];
    }
    out[1024 + n * 128 + d] = s;
}

// --------------------------- launch ------------------------------------------

extern "C" void kernel_launch(void* const* d_in, const int* in_sizes, int n_in,
                              void* d_out, int out_size, void* d_ws, size_t ws_size,
                              hipStream_t stream) {
    const float* context = (const float*)d_in[0];
    const float* frame = (const float*)d_in[1];
    const float* Vw = (const float*)d_in[6];
    const float* Vb = (const float*)d_in[7];
    const float* Ow = (const float*)d_in[8];
    const float* Ob = (const float*)d_in[9];
    const float* gamma = (const float*)d_in[10];
    const float* beta = (const float*)d_in[11];
    const float* tpw = (const float*)d_in[12];
    const float* tpb = (const float*)d_in[13];
    const float* u1w = (const float*)d_in[14];
    const float* u1b = (const float*)d_in[15];
    const float* u2w = (const float*)d_in[16];
    const float* u2b = (const float*)d_in[17];
    float* ws = (float*)d_ws;
    float* out = (float*)d_out;

    float* X0 = ws + OFF_X0;
    float* X1 = ws + OFF_X1;
    unsigned short* XB = (unsigned short*)(ws + OFF_XB);
    unsigned short* VNB = (unsigned short*)(ws + OFF_VNB);
    unsigned short* WB1 = (unsigned short*)(ws + OFF_WB1);
    unsigned short* WB2 = (unsigned short*)(ws + OFF_WB2);
    float* ST = ws + OFF_ST;
    float* GP = ws + OFF_GP;
    unsigned short* TWB = (unsigned short*)(ws + OFF_TWB);
    float* R = ws + OFF_R;
    float* HP2 = ws + OFF_HP2;
    unsigned short* HP1B = (unsigned short*)(ws + OFF_HP1B);
    unsigned short* F0B = (unsigned short*)(ws + OFF_F0B);
    unsigned short* W1B = (unsigned short*)(ws + OFF_W1B);
    unsigned short* W2B = (unsigned short*)(ws + OFF_W2B);
    float* SG = ws + OFF_SG;
    float* PP = ws + OFF_PP;

    // context [8][6][1024][144] -> X0 f32 + XB bf16 (pixel-major)
    transpose_cm_pm<1><<<dim3(HWP / 16, DIN / 64, B_ * TC), dim3(16, 16), 0, stream>>>(
        context, X0, XB, DIN, HWP);

    float* Xin = X0;
    float* Y = X1;
    for (int l = 0; l < 2; ++l) {
        wb_plain<<<(DFF * DIN) / 256, 256, 0, stream>>>(Vw + (size_t)l * DFF * DIN, WB1, DFF, DIN);
        wb_plain<<<(DIN * DFF) / 256, 256, 0, stream>>>(Ow + (size_t)l * DIN * DFF, WB2, DIN, DFF);
        // VN = relu(X*Vw^T + Vb)  [bf16 out]
        gemm_mfma<11, 0, 0><<<dim3(DFF / 128, P_CTX / 128, 1), 256, 0, stream>>>(
            XB, WB1, Vb + l * DFF, nullptr, VNB, P_CTX, DFF, DIN, 0, 0, 0, 0, 0, 0);
        // Y = X + relu(VN*Ow^T + Ob)  [f32 out]
        gemm_mfma<7, 0, 0><<<dim3(DIN / 128, P_CTX / 128, 1), 256, 0, stream>>>(
            VNB, WB2, Ob + l * DIN, Xin, Y, P_CTX, DIN, DFF, 0, 0, 0, 0, 0, 0);
        // BatchNorm (training-mode stats) in place on Y; bf16 copy -> XB
        zero_f32<<<8, 256, 0, stream>>>(ST, 2048);
        bn_stats<<<P_CTX / 64, 256, 0, stream>>>(Y, ST);
        bn_final<<<4, 256, 0, stream>>>(ST, gamma + l * DIN, beta + l * DIN);
        bn_apply_b<<<(P_CTX * DIN / 4) / 256, 256, 0, stream>>>(Y, XB, ST);
        float* t = Xin;
        Xin = Y;
        Y = t;
    }

    // temporal pool: split-K GEMM over 27 taps (A rows gathered from XB)
    wb_conv<<<(27 * DIN * DOUT) / 256, 256, 0, stream>>>(tpw, TWB);
    gemm_mfma<0, 0, 1><<<dim3(1, NPOS / 128, 27), 256, 0, stream>>>(
        XB, TWB, nullptr, nullptr, GP, NPOS, DOUT, DIN,
        (size_t)DIN / 8 * DOUT * 8, (size_t)NPOS * DOUT, 0, 0, 0, 0);
    conv3_reduce<<<(NPOS * DOUT) / 256, 256, 0, stream>>>(GP, tpb, R);
    goal_reduce<<<8, 128, 0, stream>>>(R, out);

    // frame upsample path (bf16 activations throughout)
    transpose_cm_pm<0><<<dim3(HWP / 16, DIN / 64, NF), dim3(16, 16), 0, stream>>>(
        frame, nullptr, F0B, DIN, HWP);
    wb_convT<<<(4 * DIN * DFF) / 256, 256, 0, stream>>>(u1w, W1B, DFF, DIN);
    wb_convT<<<(4 * DFF * DOUT) / 256, 256, 0, stream>>>(u2w, W2B, DOUT, DFF);
    // up1: relu(convT1), 4 quadrants via blockIdx.z, bf16 out with row remap
    gemm_mfma<11, 1, 0><<<dim3(DFF / 128, P_FRM / 128, 4), 256, 0, stream>>>(
        F0B, W1B, u1b, nullptr, HP1B, P_FRM, DFF, DIN,
        (size_t)DIN / 8 * DFF * 8, 0, 12, 144, 24, 576);
    // up2: convT2 (no relu), f32 out with row remap -> HP2
    gemm_mfma<1, 1, 0><<<dim3(DOUT / 128, P_H1 / 128, 4), 256, 0, stream>>>(
        HP1B, W2B, u2b, nullptr, HP2, P_H1, DOUT, DFF,
        (size_t)DFF / 8 * DOUT * 8, 0, 24, 576, 48, 2304);

    // final goal/state attention
    attn_logits<<<dim3(S2 / 16, NF), 256, 0, stream>>>(HP2, out, SG);
    attn_softmax<<<NF, 256, 0, stream>>>(SG);
    attn_pv<<<dim3(18, NF), 256, 0, stream>>>(HP2, SG, PP);
    attn_pv_reduce<<<NF, 128, 0, stream>>>(PP, out);
}